// Round 1
// baseline (414.393 us; speedup 1.0000x reference)
//
#include <hip/hip_runtime.h>
#include <stdint.h>

#define NN 20000
#define MM 16000
#define DD 128
#define CT2 250       // 16000 / 64 col-tiles
#define SPLITS 32     // multiple of 8 -> split % 8 == XCD id (L2 locality)
#define RB2 40        // ceil(20000/512) row blocks of 512

typedef unsigned long long u64;
typedef _Float16 f16x8 __attribute__((ext_vector_type(8)));
typedef float f32x16 __attribute__((ext_vector_type(16)));

// One wave per rain row: y2[m] = ||rain[m]||^2 (fp32, unbiased)
__global__ void k_y2(const float* __restrict__ rain, float* __restrict__ y2) {
    int row = blockIdx.x * 4 + (threadIdx.x >> 6);
    int lane = threadIdx.x & 63;
    if (row >= MM) return;
    float2 v = ((const float2*)(rain + (size_t)row * DD))[lane];
    float s = v.x * v.x + v.y * v.y;
    #pragma unroll
    for (int off = 32; off > 0; off >>= 1) s += __shfl_down(s, off);
    if (lane == 0) y2[row] = s;
}

// Split rain into fp16 hi/lo 64-col tile images (32KB per tile):
// tile tc: hi f16[0:8192], lo f16[8192:16384]
__global__ void k_split_B(const float* __restrict__ rain, _Float16* __restrict__ Bimg) {
    int id = blockIdx.x * 256 + threadIdx.x;
    if (id >= CT2 * 1024) return;
    int cl = id & 31;
    int cg = (id >> 5) & 1;
    int kp = (id >> 6) & 15;           // ks = kp>>1, kh = kp&1
    int tc = id >> 10;
    int row = tc * 64 + cg * 32 + cl;
    const float4* src = (const float4*)(rain + (size_t)row * DD + kp * 8);
    float4 v0 = src[0], v1 = src[1];
    float x[8] = {v0.x, v0.y, v0.z, v0.w, v1.x, v1.y, v1.z, v1.w};
    _Float16 hi[8], lo[8];
    #pragma unroll
    for (int j = 0; j < 8; ++j) {
        _Float16 h = (_Float16)x[j];
        hi[j] = h;
        lo[j] = (_Float16)(x[j] - (float)h);
    }
    int ks = kp >> 1, kh = kp & 1;
    int chunk = ((ks * 2 + cg) * 2 + kh) * 32 + cl;
    size_t base = (size_t)tc * 16384;
    *(f16x8*)(Bimg + base + (size_t)chunk * 8) = *(f16x8*)hi;
    *(f16x8*)(Bimg + base + 8192 + (size_t)chunk * 8) = *(f16x8*)lo;
}

// W1 -> fp16 B-image for the MLP GEMM: chunk c = ((ks*4+cg)*2+kh)*32+cl;
// B[k][d] = W1[d][k], k = ks*16+kh*8+j, d = cg*32+cl. 4096 chunks = 64KB.
__global__ void k_w1img(const float* __restrict__ W1, _Float16* __restrict__ W1img) {
    int id = blockIdx.x * 256 + threadIdx.x;
    if (id >= 4096) return;
    int cl = id & 31;
    int kh = (id >> 5) & 1;
    int cg = (id >> 6) & 3;
    int ks = id >> 8;
    int d = cg * 32 + cl;
    int k = ks * 16 + kh * 8;
    const float4* src = (const float4*)(W1 + (size_t)d * 256 + k);
    float4 v0 = src[0], v1 = src[1];
    float x[8] = {v0.x, v0.y, v0.z, v0.w, v1.x, v1.y, v1.z, v1.w};
    _Float16 h[8];
    #pragma unroll
    for (int j = 0; j < 8; ++j) h[j] = (_Float16)x[j];
    *(f16x8*)(W1img + (size_t)id * 8) = *(f16x8*)h;
}

// MFMA distance GEMM + fused argmin.
// NEW: 512-thread blocks (8 waves, 512 rows), TRIPLE-buffered 32KB tiles,
// raw s_barrier + COUNTED vmcnt(4) at tile boundaries (T4: never drain to 0
// in the main loop), setprio(1) around MFMA clusters (T5). One barrier/tile.
__global__ __launch_bounds__(512, 2) void k_dist(
        const float* __restrict__ clear_f,
        const _Float16* __restrict__ Bimg, const float* __restrict__ y2,
        u64* __restrict__ keys2) {
    __shared__ _Float16 lds[3][16384];   // 3 x 32KB B-tile ring (96KB)
    __shared__ float y2s[512];           // [tile][col-in-tile], nt*64 <= 512

    const int tid = threadIdx.x;
    const int w = tid >> 6, lane = tid & 63;
    const int l5 = lane >> 5, l31 = lane & 31;
    const int b = blockIdx.x;
    const int split = b & 31;
    const int n0 = (b >> 5) * 512;
    const int nt = (CT2 - split + SPLITS - 1) / SPLITS;   // 7 or 8

    // per-wave: 4 of 32 1KB segs per tile (wave-uniform LDS base + lane*16)
    #define STAGE(T, BUF) do {                                                 \
        const _Float16* gsrc_ = Bimg + (size_t)(T) * 16384;                    \
        _Float16* dst_ = &lds[BUF][0];                                         \
        _Pragma("unroll")                                                      \
        for (int n_ = 0; n_ < 4; ++n_) {                                       \
            int seg_ = w * 4 + n_;                                             \
            __builtin_amdgcn_global_load_lds(                                  \
                (const __attribute__((address_space(1))) unsigned int*)        \
                    (gsrc_ + (size_t)seg_ * 512 + (size_t)lane * 8),           \
                (__attribute__((address_space(3))) unsigned int*)              \
                    (dst_ + (size_t)seg_ * 512),                               \
                16, 0, 0);                                                     \
        }                                                                      \
    } while (0)

    // Prologue prefetch: tiles 0 and 1 -> bufs 0,1 (8 loads in flight/wave)
    STAGE(split, 0);
    if (nt > 1) STAGE(split + SPLITS, 1);

    // Stage this split's y2 into the LDS sidecar
    for (int j = tid; j < nt * 64; j += 512) {
        int tt = j >> 6;
        int cc = j & 63;
        y2s[j] = y2[(split + tt * SPLITS) * 64 + cc];
    }

    // A fragments: lane holds A[row=l31 of rb][k=ks*16+l5*8+j], split in-kernel
    f16x8 afh[2][8], afl[2][8];
    #pragma unroll
    for (int rb = 0; rb < 2; ++rb) {
        int r = n0 + w * 64 + rb * 32 + l31;
        if (r >= NN) r = NN - 1;
        const float* ap = clear_f + (size_t)r * DD + l5 * 8;
        #pragma unroll
        for (int ks = 0; ks < 8; ++ks) {
            float4 v0 = *(const float4*)(ap + ks * 16);
            float4 v1 = *(const float4*)(ap + ks * 16 + 4);
            float x[8] = {v0.x, v0.y, v0.z, v0.w, v1.x, v1.y, v1.z, v1.w};
            _Float16 hi[8], lo[8];
            #pragma unroll
            for (int j = 0; j < 8; ++j) {
                float s = -2.f * x[j];
                _Float16 h = (_Float16)s;
                hi[j] = h;
                lo[j] = (_Float16)(s - (float)h);
            }
            afh[rb][ks] = *(f16x8*)hi;
            afl[rb][ks] = *(f16x8*)lo;
        }
    }

    // Each wave's own y2s ds_writes drained; visibility published by the
    // first in-loop barrier (y2s is read-only afterwards).
    asm volatile("s_waitcnt lgkmcnt(0)" ::: "memory");

    float bestd[32];
    unsigned bits[4] = {0u, 0u, 0u, 0u};   // nibble/slot: (tile_idx<<1)|cg
    #pragma unroll
    for (int s = 0; s < 32; ++s) bestd[s] = 1e30f;

    int p = 0;   // buffer holding tile i  (== i % 3)
    for (int i = 0; i < nt; ++i) {
        // Tile boundary: tile i's 4 segs done iff <=4 of mine outstanding
        // (in-order completion; tile i+1's 4 may stay in flight). Barrier
        // then makes ALL waves' segs for tile i visible.
        if (i + 1 < nt) {
            asm volatile("s_waitcnt vmcnt(4)" ::: "memory");
        } else {
            asm volatile("s_waitcnt vmcnt(0)" ::: "memory");
        }
        __builtin_amdgcn_s_barrier();
        __builtin_amdgcn_sched_barrier(0);   // rule #18: pin reads below barrier

        // Issue prefetch of tile i+2 into the ring slot freed at this barrier
        if (i + 2 < nt) {
            int p2 = p + 2; if (p2 >= 3) p2 -= 3;
            STAGE(split + (i + 2) * SPLITS, p2);
        }

        float y2v0 = y2s[i * 64 + l31];          // ds_read_b32, lgkmcnt only
        float y2v1 = y2s[i * 64 + 32 + l31];

        // 4 independent accumulator chains (rb x cg); C-init carries y2
        f32x16 acc00, acc01, acc10, acc11;
        #pragma unroll
        for (int e = 0; e < 16; ++e) {
            acc00[e] = y2v0; acc10[e] = y2v0;
            acc01[e] = y2v1; acc11[e] = y2v1;
        }

        const _Float16* lbuf = &lds[p][0];
        #pragma unroll
        for (int ks = 0; ks < 8; ++ks) {
            f16x8 bh0 = *(const f16x8*)(lbuf + (size_t)(ks * 2 + 0) * 512 + (size_t)lane * 8);
            f16x8 bh1 = *(const f16x8*)(lbuf + (size_t)(ks * 2 + 1) * 512 + (size_t)lane * 8);
            f16x8 bl0 = *(const f16x8*)(lbuf + 8192 + (size_t)(ks * 2 + 0) * 512 + (size_t)lane * 8);
            f16x8 bl1 = *(const f16x8*)(lbuf + 8192 + (size_t)(ks * 2 + 1) * 512 + (size_t)lane * 8);
            __builtin_amdgcn_s_setprio(1);
            acc00 = __builtin_amdgcn_mfma_f32_32x32x16_f16(afh[0][ks], bh0, acc00, 0, 0, 0);
            acc10 = __builtin_amdgcn_mfma_f32_32x32x16_f16(afh[1][ks], bh0, acc10, 0, 0, 0);
            acc01 = __builtin_amdgcn_mfma_f32_32x32x16_f16(afh[0][ks], bh1, acc01, 0, 0, 0);
            acc11 = __builtin_amdgcn_mfma_f32_32x32x16_f16(afh[1][ks], bh1, acc11, 0, 0, 0);
            acc00 = __builtin_amdgcn_mfma_f32_32x32x16_f16(afh[0][ks], bl0, acc00, 0, 0, 0);
            acc10 = __builtin_amdgcn_mfma_f32_32x32x16_f16(afh[1][ks], bl0, acc10, 0, 0, 0);
            acc01 = __builtin_amdgcn_mfma_f32_32x32x16_f16(afh[0][ks], bl1, acc01, 0, 0, 0);
            acc11 = __builtin_amdgcn_mfma_f32_32x32x16_f16(afh[1][ks], bl1, acc11, 0, 0, 0);
            acc00 = __builtin_amdgcn_mfma_f32_32x32x16_f16(afl[0][ks], bh0, acc00, 0, 0, 0);
            acc10 = __builtin_amdgcn_mfma_f32_32x32x16_f16(afl[1][ks], bh0, acc10, 0, 0, 0);
            acc01 = __builtin_amdgcn_mfma_f32_32x32x16_f16(afl[0][ks], bh1, acc01, 0, 0, 0);
            acc11 = __builtin_amdgcn_mfma_f32_32x32x16_f16(afl[1][ks], bh1, acc11, 0, 0, 0);
            __builtin_amdgcn_s_setprio(0);
        }

        // Fold: cg-pair min first (strict < prefers cg0 = lower col on tie),
        // then strict < vs running best (prefers earlier tile = lower col)
        const unsigned ibase = (unsigned)i << 1;
        #pragma unroll
        for (int e = 0; e < 16; ++e) {
            {
                float d0 = acc00[e], d1 = acc01[e];
                bool tk = d1 < d0;
                float dm = tk ? d1 : d0;
                int s = e, sh = 4 * (e & 7);
                bool up = dm < bestd[s];
                bestd[s] = up ? dm : bestd[s];
                unsigned nib = ibase | (unsigned)tk;
                bits[s >> 3] = up ? ((bits[s >> 3] & ~(15u << sh)) | (nib << sh))
                                  : bits[s >> 3];
            }
            {
                float d0 = acc10[e], d1 = acc11[e];
                bool tk = d1 < d0;
                float dm = tk ? d1 : d0;
                int s = 16 + e, sh = 4 * (s & 7);
                bool up = dm < bestd[s];
                bestd[s] = up ? dm : bestd[s];
                unsigned nib = ibase | (unsigned)tk;
                bits[s >> 3] = up ? ((bits[s >> 3] & ~(15u << sh)) | (nib << sh))
                                  : bits[s >> 3];
            }
        }

        ++p; if (p == 3) p = 0;
    }
    #undef STAGE

    // Cross-lane min over the 32 l31 lanes, then one plain store per row.
    // Monotone sign-flip map (distances can be negative near the min).
    // C/D layout: col=lane&31, row=(e&3)+8*(e>>2)+4*l5
    #pragma unroll
    for (int s = 0; s < 32; ++s) {
        unsigned nib = (bits[s >> 3] >> (4 * (s & 7))) & 15u;
        int i4 = (int)(nib >> 1), cg = (int)(nib & 1);
        int col = (split + i4 * SPLITS) * 64 + cg * 32 + l31;
        unsigned u = __float_as_uint(bestd[s]);
        u = (u & 0x80000000u) ? ~u : (u | 0x80000000u);
        u64 key = ((u64)u << 32) | (unsigned)col;
        #pragma unroll
        for (int off = 1; off < 32; off <<= 1) {
            u64 o = __shfl_xor(key, off);
            if (o < key) key = o;
        }
        if (l31 == 0) {
            int e = s & 15, rb = s >> 4;
            int grow = n0 + w * 64 + rb * 32 + (e & 3) + 8 * (e >> 2) + 4 * l5;
            if (grow < NN) keys2[(size_t)grow * SPLITS + split] = key;
        }
    }
}

// Final argmin: lane-per-split, coalesced, shfl-min within 32-lane groups.
__global__ void k_reduce(const u64* __restrict__ keys2, int* __restrict__ idx) {
    int gid = blockIdx.x * 256 + threadIdx.x;
    int row = gid >> 5, j = gid & 31;
    if (row >= NN) return;
    u64 k = keys2[(size_t)row * SPLITS + j];
    #pragma unroll
    for (int off = 16; off > 0; off >>= 1) {
        u64 o = __shfl_xor(k, off);
        if (o < k) k = o;
    }
    if (j == 0) idx[row] = (int)(k & 0xffffffffu);
}

// MLP via fp16 MFMA: 1 wave / 32 rows / block, NO LDS staging — the 64KB
// W1 image is L2-resident chip-wide (Common-mistake #7: don't stage what
// the cache fits). 625 blocks fill all 256 CUs (was 157).
__global__ __launch_bounds__(64) void k_mlp(
        const float* __restrict__ clear_f, const float* __restrict__ rain_f,
        const _Float16* __restrict__ W1img, const float* __restrict__ b1,
        const float* __restrict__ W2, const float* __restrict__ b2,
        const int* __restrict__ idx, float* __restrict__ out) {
    const int lane = threadIdx.x;
    const int l5 = lane >> 5, l31 = lane & 31;
    const int n0 = blockIdx.x * 32;

    int n = n0 + l31;
    int nc = n < NN ? n : NN - 1;
    int rid = idx[nc];
    f16x8 af[16];
    #pragma unroll
    for (int ks = 0; ks < 16; ++ks) {
        int k0 = ks * 16 + l5 * 8;
        const float4* src = (k0 < 128)
            ? (const float4*)(clear_f + (size_t)nc * DD + k0)
            : (const float4*)(rain_f + (size_t)rid * DD + (k0 - 128));
        float4 v0 = src[0], v1 = src[1];
        float x[8] = {v0.x, v0.y, v0.z, v0.w, v1.x, v1.y, v1.z, v1.w};
        _Float16 h[8];
        #pragma unroll
        for (int j = 0; j < 8; ++j) h[j] = (_Float16)x[j];
        af[ks] = *(f16x8*)h;
    }

    f32x16 acc[4];
    #pragma unroll
    for (int cg = 0; cg < 4; ++cg)
        #pragma unroll
        for (int e = 0; e < 16; ++e) acc[cg][e] = 0.f;

    #pragma unroll
    for (int ks = 0; ks < 16; ++ks) {
        #pragma unroll
        for (int cg = 0; cg < 4; ++cg) {
            f16x8 bh = *(const f16x8*)(W1img +
                ((size_t)((ks * 4 + cg) * 2 + l5)) * 256 + (size_t)l31 * 8);
            acc[cg] = __builtin_amdgcn_mfma_f32_32x32x16_f16(af[ks], bh, acc[cg], 0, 0, 0);
        }
    }

    // Epilogue: lane holds h[row(e,l5)][d = cg*32 + l31]
    float b1v[4], w2v[4];
    #pragma unroll
    for (int cg = 0; cg < 4; ++cg) {
        b1v[cg] = b1[cg * 32 + l31];
        w2v[cg] = W2[cg * 32 + l31];
    }
    float b2v = b2[0];

    #pragma unroll
    for (int e = 0; e < 16; ++e) {
        float part = 0.f;
        #pragma unroll
        for (int cg = 0; cg < 4; ++cg) {
            float hv = acc[cg][e] + b1v[cg];
            hv = hv > 0.f ? hv : 0.f;
            part = fmaf(hv, w2v[cg], part);
        }
        #pragma unroll
        for (int off = 1; off < 32; off <<= 1) part += __shfl_xor(part, off);
        float s = part + b2v;
        float wv = 1.f / (1.f + expf(-s));
        int row = n0 + (e & 3) + 8 * (e >> 2) + 4 * l5;
        if (row < NN) {
            int rid2 = idx[row];
            float4 cv = *(const float4*)(clear_f + (size_t)row * DD + l31 * 4);
            float4 av = *(const float4*)(rain_f + (size_t)rid2 * DD + l31 * 4);
            float4 ov;
            ov.x = wv * cv.x + (1.f - wv) * av.x;
            ov.y = wv * cv.y + (1.f - wv) * av.y;
            ov.z = wv * cv.z + (1.f - wv) * av.z;
            ov.w = wv * cv.w + (1.f - wv) * av.w;
            *(float4*)(out + (size_t)row * DD + l31 * 4) = ov;
        }
    }
}

extern "C" void kernel_launch(void* const* d_in, const int* in_sizes, int n_in,
                              void* d_out, int out_size, void* d_ws, size_t ws_size,
                              hipStream_t stream) {
    const float* clear_f = (const float*)d_in[0];
    const float* rain_f = (const float*)d_in[1];
    const float* W1 = (const float*)d_in[2];
    const float* b1 = (const float*)d_in[3];
    const float* W2 = (const float*)d_in[4];
    const float* b2 = (const float*)d_in[5];
    float* out = (float*)d_out;

    char* ws = (char*)d_ws;
    u64* keys2 = (u64*)ws;                                 // 5,120,000 B
    int* idx = (int*)(ws + 5120000);                       // 80,000 B
    float* y2 = (float*)(ws + 5200000);                    // 64,000 B
    _Float16* Bimg = (_Float16*)(ws + 5264000);            // 8,192,000 B
    _Float16* W1img = (_Float16*)(ws + 13456000);          // 65,536 B  (end 13.52MB)

    k_y2<<<MM / 4, 256, 0, stream>>>(rain_f, y2);
    k_split_B<<<(CT2 * 1024 + 255) / 256, 256, 0, stream>>>(rain_f, Bimg);
    k_w1img<<<16, 256, 0, stream>>>(W1, W1img);
    k_dist<<<RB2 * SPLITS, 512, 0, stream>>>(clear_f, Bimg, y2, keys2);
    k_reduce<<<(NN * 32 + 255) / 256, 256, 0, stream>>>(keys2, idx);
    k_mlp<<<(NN + 31) / 32, 64, 0, stream>>>(clear_f, rain_f, W1img, b1, W2, b2, idx, out);
}

// Round 2
// 357.317 us; speedup vs baseline: 1.1597x; 1.1597x over previous
//
#include <hip/hip_runtime.h>
#include <stdint.h>

#define NN 20000
#define MM 16000
#define DD 128
#define CT 500        // 16000 / 32 col-tiles (32 cols each)
#define SPLITS 32     // multiple of 8 -> split % 8 == XCD id (L2 locality)
#define RBG 157       // ceil(20000/128) row blocks of 128

typedef unsigned long long u64;
typedef _Float16 f16x8 __attribute__((ext_vector_type(8)));
typedef float f32x16 __attribute__((ext_vector_type(16)));

// One wave per rain row: y2[m] = ||rain[m]||^2 (fp32, unbiased)
__global__ void k_y2(const float* __restrict__ rain, float* __restrict__ y2) {
    int row = blockIdx.x * 4 + (threadIdx.x >> 6);
    int lane = threadIdx.x & 63;
    if (row >= MM) return;
    float2 v = ((const float2*)(rain + (size_t)row * DD))[lane];
    float s = v.x * v.x + v.y * v.y;
    #pragma unroll
    for (int off = 32; off > 0; off >>= 1) s += __shfl_down(s, off);
    if (lane == 0) y2[row] = s;
}

// Split rain into fp16 hi/lo 32-col tile images (16KB per tile):
// tile tc: hi f16[0:4096], lo f16[4096:8192]
// chunk(ks,kh,cl) = (ks*2+kh)*32+cl; payload = 8 consecutive k,
// k = ks*16+kh*8+j, col = cl.  Read side: offset = ks*512 + lane*8.
__global__ void k_split_B(const float* __restrict__ rain, _Float16* __restrict__ Bimg) {
    int id = blockIdx.x * 256 + threadIdx.x;
    if (id >= CT * 512) return;
    int cl = id & 31;
    int kh = (id >> 5) & 1;
    int ks = (id >> 6) & 7;
    int tc = id >> 9;
    int m = tc * 32 + cl;
    const float4* src = (const float4*)(rain + (size_t)m * DD + ks * 16 + kh * 8);
    float4 v0 = src[0], v1 = src[1];
    float x[8] = {v0.x, v0.y, v0.z, v0.w, v1.x, v1.y, v1.z, v1.w};
    _Float16 hi[8], lo[8];
    #pragma unroll
    for (int j = 0; j < 8; ++j) {
        _Float16 h = (_Float16)x[j];
        hi[j] = h;
        lo[j] = (_Float16)(x[j] - (float)h);
    }
    int chunk = (ks * 2 + kh) * 32 + cl;
    size_t base = (size_t)tc * 8192;
    *(f16x8*)(Bimg + base + (size_t)chunk * 8) = *(f16x8*)hi;
    *(f16x8*)(Bimg + base + 4096 + (size_t)chunk * 8) = *(f16x8*)lo;
}

// W1 -> fp16 B-image for the MLP GEMM: chunk c = ((ks*4+cg)*2+kh)*32+cl;
// B[k][d] = W1[d][k], k = ks*16+kh*8+j, d = cg*32+cl. 4096 chunks = 64KB.
__global__ void k_w1img(const float* __restrict__ W1, _Float16* __restrict__ W1img) {
    int id = blockIdx.x * 256 + threadIdx.x;
    if (id >= 4096) return;
    int cl = id & 31;
    int kh = (id >> 5) & 1;
    int cg = (id >> 6) & 3;
    int ks = id >> 8;
    int d = cg * 32 + cl;
    int k = ks * 16 + kh * 8;
    const float4* src = (const float4*)(W1 + (size_t)d * 256 + k);
    float4 v0 = src[0], v1 = src[1];
    float x[8] = {v0.x, v0.y, v0.z, v0.w, v1.x, v1.y, v1.z, v1.w};
    _Float16 h[8];
    #pragma unroll
    for (int j = 0; j < 8; ++j) h[j] = (_Float16)x[j];
    *(f16x8*)(W1img + (size_t)id * 8) = *(f16x8*)h;
}

// MFMA distance GEMM + fused argmin.
// v3: 32-col tiles (16KB), rb=1 (32 rows/wave, 128 rows/block) -> LDS 33KB,
// ~155 VGPR -> __launch_bounds__(256,3): 3 INDEPENDENT blocks/CU (12 waves),
// separate barrier clocks dovetail MFMA/VALU across blocks. Proven round-0
// schedule: prefetch-at-top, one __syncthreads per tile.
__global__ __launch_bounds__(256, 3) void k_dist(
        const float* __restrict__ clear_f,
        const _Float16* __restrict__ Bimg, const float* __restrict__ y2,
        u64* __restrict__ keys2) {
    __shared__ _Float16 lds[2][8192];   // 2 x 16KB B-tile images
    __shared__ float y2s[512];          // [tile][col-in-tile], nt*32 <= 512

    const int tid = threadIdx.x;
    const int w = tid >> 6, lane = tid & 63;
    const int l5 = lane >> 5, l31 = lane & 31;
    const int b = blockIdx.x;
    const int split = b & 31;
    const int n0 = (b >> 5) * 128;
    const int nt = (CT - split + SPLITS - 1) / SPLITS;   // 15 or 16

    // per-wave: 4 of 16 1KB segs per tile (wave-uniform LDS base + lane*16)
    #define STAGE(T, BUF) do {                                                 \
        const _Float16* gsrc_ = Bimg + (size_t)(T) * 8192;                     \
        _Float16* dst_ = &lds[BUF][0];                                         \
        _Pragma("unroll")                                                      \
        for (int n_ = 0; n_ < 4; ++n_) {                                       \
            int seg_ = w * 4 + n_;                                             \
            __builtin_amdgcn_global_load_lds(                                  \
                (const __attribute__((address_space(1))) unsigned int*)        \
                    (gsrc_ + (size_t)seg_ * 512 + (size_t)lane * 8),           \
                (__attribute__((address_space(3))) unsigned int*)              \
                    (dst_ + (size_t)seg_ * 512),                               \
                16, 0, 0);                                                     \
        }                                                                      \
    } while (0)

    // Prologue prefetch: tile 0 -> buf 0
    STAGE(split, 0);

    // Stage this split's y2 into the LDS sidecar
    for (int j = tid; j < nt * 32; j += 256) {
        int tt = j >> 5;
        int cc = j & 31;
        y2s[j] = y2[(split + tt * SPLITS) * 32 + cc];
    }

    // A fragments: lane holds A[row=l31][k=ks*16+l5*8+j] of -2*clear
    f16x8 afh[8], afl[8];
    {
        int r = n0 + w * 32 + l31;
        if (r >= NN) r = NN - 1;
        const float* ap = clear_f + (size_t)r * DD + l5 * 8;
        #pragma unroll
        for (int ks = 0; ks < 8; ++ks) {
            float4 v0 = *(const float4*)(ap + ks * 16);
            float4 v1 = *(const float4*)(ap + ks * 16 + 4);
            float x[8] = {v0.x, v0.y, v0.z, v0.w, v1.x, v1.y, v1.z, v1.w};
            _Float16 hi[8], lo[8];
            #pragma unroll
            for (int j = 0; j < 8; ++j) {
                float s = -2.f * x[j];
                _Float16 h = (_Float16)s;
                hi[j] = h;
                lo[j] = (_Float16)(s - (float)h);
            }
            afh[ks] = *(f16x8*)hi;
            afl[ks] = *(f16x8*)lo;
        }
    }

    __syncthreads();   // buf 0 + y2s ready

    float bestd[16];
    unsigned bits[2] = {0u, 0u};   // nibble/slot = tile_idx (0..15)
    #pragma unroll
    for (int s = 0; s < 16; ++s) bestd[s] = 1e30f;

    int p = 0;
    for (int i = 0; i < nt; ++i) {
        // Prefetch next tile into the other buffer (overlaps compute on buf p)
        if (i + 1 < nt) STAGE(split + (i + 1) * SPLITS, 1 - p);

        float y2v = y2s[i * 32 + l31];           // ds_read_b32, lgkmcnt only

        // Two independent accumulator chains; C-init carries y2
        f32x16 accA, accB;
        #pragma unroll
        for (int e = 0; e < 16; ++e) { accA[e] = y2v; accB[e] = 0.f; }

        const _Float16* lbuf = &lds[p][0];
        #pragma unroll
        for (int ks = 0; ks < 8; ++ks) {
            f16x8 bh = *(const f16x8*)(lbuf + (size_t)ks * 512 + (size_t)lane * 8);
            f16x8 bl = *(const f16x8*)(lbuf + 4096 + (size_t)ks * 512 + (size_t)lane * 8);
            __builtin_amdgcn_s_setprio(1);
            accA = __builtin_amdgcn_mfma_f32_32x32x16_f16(afh[ks], bh, accA, 0, 0, 0);
            accB = __builtin_amdgcn_mfma_f32_32x32x16_f16(afl[ks], bh, accB, 0, 0, 0);
            accA = __builtin_amdgcn_mfma_f32_32x32x16_f16(afh[ks], bl, accA, 0, 0, 0);
            __builtin_amdgcn_s_setprio(0);
        }

        // Fold into 16 running slots; strict < prefers earlier tile = lower col
        const unsigned nib = (unsigned)i;
        #pragma unroll
        for (int e = 0; e < 16; ++e) {
            float d = accA[e] + accB[e];
            int sh = 4 * (e & 7);
            bool up = d < bestd[e];
            bestd[e] = up ? d : bestd[e];
            bits[e >> 3] = up ? ((bits[e >> 3] & ~(15u << sh)) | (nib << sh))
                              : bits[e >> 3];
        }

        __syncthreads();   // publishes prefetch (buf 1-p), frees buf p
        p ^= 1;
    }
    #undef STAGE

    // Cross-lane min over the 32 l31 lanes, then one plain store per row.
    // Monotone sign-flip map (distances can be negative near the min).
    // C/D layout: col=lane&31, row=(e&3)+8*(e>>2)+4*l5
    #pragma unroll
    for (int s = 0; s < 16; ++s) {
        unsigned nib = (bits[s >> 3] >> (4 * (s & 7))) & 15u;
        int col = (split + (int)nib * SPLITS) * 32 + l31;
        unsigned u = __float_as_uint(bestd[s]);
        u = (u & 0x80000000u) ? ~u : (u | 0x80000000u);
        u64 key = ((u64)u << 32) | (unsigned)col;
        #pragma unroll
        for (int off = 1; off < 32; off <<= 1) {
            u64 o = __shfl_xor(key, off);
            if (o < key) key = o;
        }
        if (l31 == 0) {
            int grow = n0 + w * 32 + (s & 3) + 8 * (s >> 2) + 4 * l5;
            if (grow < NN) keys2[(size_t)grow * SPLITS + split] = key;
        }
    }
}

// Final argmin: lane-per-split, coalesced, shfl-min within 32-lane groups.
__global__ void k_reduce(const u64* __restrict__ keys2, int* __restrict__ idx) {
    int gid = blockIdx.x * 256 + threadIdx.x;
    int row = gid >> 5, j = gid & 31;
    if (row >= NN) return;
    u64 k = keys2[(size_t)row * SPLITS + j];
    #pragma unroll
    for (int off = 16; off > 0; off >>= 1) {
        u64 o = __shfl_xor(k, off);
        if (o < k) k = o;
    }
    if (j == 0) idx[row] = (int)(k & 0xffffffffu);
}

// MLP via fp16 MFMA: 1 wave / 32 rows / block, NO LDS staging — the 64KB
// W1 image is L2-resident chip-wide. 625 blocks fill all 256 CUs.
__global__ __launch_bounds__(64) void k_mlp(
        const float* __restrict__ clear_f, const float* __restrict__ rain_f,
        const _Float16* __restrict__ W1img, const float* __restrict__ b1,
        const float* __restrict__ W2, const float* __restrict__ b2,
        const int* __restrict__ idx, float* __restrict__ out) {
    const int lane = threadIdx.x;
    const int l5 = lane >> 5, l31 = lane & 31;
    const int n0 = blockIdx.x * 32;

    int n = n0 + l31;
    int nc = n < NN ? n : NN - 1;
    int rid = idx[nc];
    f16x8 af[16];
    #pragma unroll
    for (int ks = 0; ks < 16; ++ks) {
        int k0 = ks * 16 + l5 * 8;
        const float4* src = (k0 < 128)
            ? (const float4*)(clear_f + (size_t)nc * DD + k0)
            : (const float4*)(rain_f + (size_t)rid * DD + (k0 - 128));
        float4 v0 = src[0], v1 = src[1];
        float x[8] = {v0.x, v0.y, v0.z, v0.w, v1.x, v1.y, v1.z, v1.w};
        _Float16 h[8];
        #pragma unroll
        for (int j = 0; j < 8; ++j) h[j] = (_Float16)x[j];
        af[ks] = *(f16x8*)h;
    }

    f32x16 acc[4];
    #pragma unroll
    for (int cg = 0; cg < 4; ++cg)
        #pragma unroll
        for (int e = 0; e < 16; ++e) acc[cg][e] = 0.f;

    #pragma unroll
    for (int ks = 0; ks < 16; ++ks) {
        #pragma unroll
        for (int cg = 0; cg < 4; ++cg) {
            f16x8 bh = *(const f16x8*)(W1img +
                ((size_t)((ks * 4 + cg) * 2 + l5)) * 256 + (size_t)l31 * 8);
            acc[cg] = __builtin_amdgcn_mfma_f32_32x32x16_f16(af[ks], bh, acc[cg], 0, 0, 0);
        }
    }

    // Epilogue: lane holds h[row(e,l5)][d = cg*32 + l31]
    float b1v[4], w2v[4];
    #pragma unroll
    for (int cg = 0; cg < 4; ++cg) {
        b1v[cg] = b1[cg * 32 + l31];
        w2v[cg] = W2[cg * 32 + l31];
    }
    float b2v = b2[0];

    #pragma unroll
    for (int e = 0; e < 16; ++e) {
        float part = 0.f;
        #pragma unroll
        for (int cg = 0; cg < 4; ++cg) {
            float hv = acc[cg][e] + b1v[cg];
            hv = hv > 0.f ? hv : 0.f;
            part = fmaf(hv, w2v[cg], part);
        }
        #pragma unroll
        for (int off = 1; off < 32; off <<= 1) part += __shfl_xor(part, off);
        float s = part + b2v;
        float wv = 1.f / (1.f + expf(-s));
        int row = n0 + (e & 3) + 8 * (e >> 2) + 4 * l5;
        if (row < NN) {
            int rid2 = idx[row];
            float4 cv = *(const float4*)(clear_f + (size_t)row * DD + l31 * 4);
            float4 av = *(const float4*)(rain_f + (size_t)rid2 * DD + l31 * 4);
            float4 ov;
            ov.x = wv * cv.x + (1.f - wv) * av.x;
            ov.y = wv * cv.y + (1.f - wv) * av.y;
            ov.z = wv * cv.z + (1.f - wv) * av.z;
            ov.w = wv * cv.w + (1.f - wv) * av.w;
            *(float4*)(out + (size_t)row * DD + l31 * 4) = ov;
        }
    }
}

extern "C" void kernel_launch(void* const* d_in, const int* in_sizes, int n_in,
                              void* d_out, int out_size, void* d_ws, size_t ws_size,
                              hipStream_t stream) {
    const float* clear_f = (const float*)d_in[0];
    const float* rain_f = (const float*)d_in[1];
    const float* W1 = (const float*)d_in[2];
    const float* b1 = (const float*)d_in[3];
    const float* W2 = (const float*)d_in[4];
    const float* b2 = (const float*)d_in[5];
    float* out = (float*)d_out;

    char* ws = (char*)d_ws;
    u64* keys2 = (u64*)ws;                                 // 5,120,000 B
    int* idx = (int*)(ws + 5120000);                       // 80,000 B
    float* y2 = (float*)(ws + 5200000);                    // 64,000 B
    _Float16* Bimg = (_Float16*)(ws + 5264000);            // 8,192,000 B
    _Float16* W1img = (_Float16*)(ws + 13456000);          // 65,536 B  (end 13.52MB)

    k_y2<<<MM / 4, 256, 0, stream>>>(rain_f, y2);
    k_split_B<<<(CT * 512 + 255) / 256, 256, 0, stream>>>(rain_f, Bimg);
    k_w1img<<<16, 256, 0, stream>>>(W1, W1img);
    k_dist<<<RBG * SPLITS, 256, 0, stream>>>(clear_f, Bimg, y2, keys2);
    k_reduce<<<(NN * 32 + 255) / 256, 256, 0, stream>>>(keys2, idx);
    k_mlp<<<(NN + 31) / 32, 64, 0, stream>>>(clear_f, rain_f, W1img, b1, W2, b2, idx, out);
}